// Round 16
// baseline (333.833 us; speedup 1.0000x reference)
//
// DeltaNet forward, MI355X/gfx950. Round 16: consolidation — beta/floor folded into
// the QKV GEMM (N=3200, EPI=3 epilogue; 16 real + 112 zero B-rows in side buffer),
// cvt folded into prep_k. 11 -> 9 launches. r15 = 331 µs. 8-phase GEMM port
// rejected: guide m248 shows ~848 TF at K=1024 (vs our 888 at m97 structure).
#include <hip/hip_runtime.h>
#include <hip/hip_bf16.h>
#include <cstdint>
#include <cstddef>

#define DEVI static __device__ __forceinline__

typedef __attribute__((ext_vector_type(4))) float f32x4;
typedef __attribute__((ext_vector_type(8))) short s16x8;
typedef unsigned short u16;
typedef unsigned int u32;

DEVI float bf2f(u16 u){ u32 x = ((u32)u) << 16; float f; __builtin_memcpy(&f, &x, 4); return f; }
DEVI u16 f2bf(float f){ u32 x; __builtin_memcpy(&x, &f, 4); u32 r = x + 0x7fffu + ((x >> 16) & 1u); return (u16)(r >> 16); }
DEVI float sigm(float x){ return 1.0f / (1.0f + __expf(-x)); }
DEVI f32x4 mfma16(s16x8 a, s16x8 b, f32x4 c){ return __builtin_amdgcn_mfma_f32_16x16x32_bf16(a, b, c, 0, 0, 0); }
DEVI s16x8 pack8(float4 a, float4 b){
  s16x8 v;
  v[0]=(short)f2bf(a.x); v[1]=(short)f2bf(a.y); v[2]=(short)f2bf(a.z); v[3]=(short)f2bf(a.w);
  v[4]=(short)f2bf(b.x); v[5]=(short)f2bf(b.y); v[6]=(short)f2bf(b.z); v[7]=(short)f2bf(b.w);
  return v;
}
// packed bf16x2 from two f32 (RNE) — no builtin on gfx950, single VOP3 via asm
DEVI u32 pkbf(float lo, float hi){
  u32 d; asm("v_cvt_pk_bf16_f32 %0, %1, %2" : "=v"(d) : "v"(lo), "v"(hi));
  return d;
}
// two 8B-aligned LDS reads (stride-44 u16 rows are 8B- but not 16B-aligned)
DEVI s16x8 ld_tr(const u16* p){
  short4 a = *(const short4*)p;
  short4 b = *(const short4*)(p + 4);
  s16x8 v; v[0]=a.x; v[1]=a.y; v[2]=a.z; v[3]=a.w; v[4]=b.x; v[5]=b.y; v[6]=b.z; v[7]=b.w;
  return v;
}

// async global->LDS, 16B per lane; LDS dest is wave-uniform base + lane*16.
#define GLL16(gp, lp) __builtin_amdgcn_global_load_lds( \
    (const __attribute__((address_space(1))) void*)(gp), \
    (__attribute__((address_space(3))) void*)(lp), 16, 0, 0)

// ---------------- merged prep: transposes + w2pack + wbfT + hs->bf16 ----------------
// blocks [0,3072) Wq/Wk/Wv, [3072,5120) W1, [5120,6144) Wo,
// [6144,6272) w2pack, [6272,6288) wbfT ([Wb|Wfl]^T padded to 128 rows),
// [6288,14480) hs -> bf16.
DEVI void transpose_tile(const float* src, u16* dst, int K, int N,
                         int n0, int k0, int t){
  __shared__ float tile[32][33];
  const int cc = t & 31, rb = t >> 5;
  #pragma unroll
  for (int it = 0; it < 4; ++it){ int rr = rb + it*8; tile[rr][cc] = src[(size_t)(k0+rr)*N + n0 + cc]; }
  __syncthreads();
  #pragma unroll
  for (int it = 0; it < 4; ++it){ int rr = rb + it*8; dst[(size_t)(n0+rr)*K + k0 + cc] = f2bf(tile[cc][rr]); }
}

__global__ __launch_bounds__(256) void prep_k(
    const float* __restrict__ Wq, const float* __restrict__ Wk, const float* __restrict__ Wv,
    const float* __restrict__ W1, const float* __restrict__ Wo,
    const float* __restrict__ W2, const float* __restrict__ Wb, const float* __restrict__ Wfl,
    const float* __restrict__ hs,
    u16* __restrict__ wqT, u16* __restrict__ wkT, u16* __restrict__ wvT,
    u16* __restrict__ w1T, u16* __restrict__ woT,
    u16* __restrict__ w2p, u16* __restrict__ wbfT, u16* __restrict__ hsb)
{
  const int blk = blockIdx.x, t = threadIdx.x;
  if (blk < 3072){
    const int which = blk >> 10, tile = blk & 1023;
    const float* src = (which == 0) ? Wq : (which == 1) ? Wk : Wv;
    u16* dst = (which == 0) ? wqT : (which == 1) ? wkT : wvT;
    transpose_tile(src, dst, 1024, 1024, (tile & 31)*32, (tile >> 5)*32, t);
  } else if (blk < 5120){
    const int tile = blk - 3072;
    transpose_tile(W1, w1T, 1024, 2048, (tile & 63)*32, (tile >> 6)*32, t);
  } else if (blk < 6144){
    const int tile = blk - 5120;
    transpose_tile(Wo, woT, 1024, 1024, (tile & 31)*32, (tile >> 5)*32, t);
  } else if (blk < 6272){
    if (t < 64){
      const int i = blk - 6144, kt = i & 63, nt = i >> 6;
      const int lane = t, g = lane >> 4, r = lane & 15;
      float v[8];
      #pragma unroll
      for (int j=0;j<8;++j) v[j] = W2[(size_t)(kt*32 + g*8 + j)*32 + nt*16 + r];
      *(s16x8*)(w2p + (((size_t)kt*2 + nt)*64 + lane)*8) =
          pack8(make_float4(v[0],v[1],v[2],v[3]), make_float4(v[4],v[5],v[6],v[7]));
    }
  } else if (blk < 6288){
    // wbfT rows 8i..8i+7 of [128][1024]: rows<8 = Wb^T, rows 8..15 = Wfl^T, rest 0
    const int i = blk - 6272;
    for (int e = t; e < 8*1024; e += 256){
      const int row = i*8 + (e >> 10), k = e & 1023;
      float v = 0.f;
      if (row < 8) v = Wb[(size_t)k*8 + row];
      else if (row < 16) v = Wfl[(size_t)k*8 + (row-8)];
      wbfT[(size_t)row*1024 + k] = f2bf(v);
    }
  } else {
    const int i = (blk - 6288)*256 + t;   // i < 2097152
    float4 v = ((const float4*)hs)[i];
    ushort4 o; o.x = f2bf(v.x); o.y = f2bf(v.y); o.z = f2bf(v.z); o.w = f2bf(v.w);
    ((ushort4*)hsb)[i] = o;
  }
}

// ---------------- GEMM: A[M][K]bf16 @ Bt[N][K]bf16 -> C[M][N] ----------------
// 128x128 tile, BK=64, 4 waves (2x2), 4x4 16x16 frags/wave.
// LDS: pre-swizzled global source + XOR'd ds_read (both-sides swizzle).
// Bijective XCD block swizzle (nwg % 8 == 0 for all grids).
// EPI: 1 = +bias+gelu bf16, 2 = fp32,
//      3 = QKV+beta/floor: cols<3072 split-store q/k/v; tile n0==3072 reads Bt2
//          ([Wb|Wfl]^T padded) and writes beta/flo (bias arg = flb).
template<int EPI>
__global__ __launch_bounds__(256, 2) void gemm_bt(
    const u16* __restrict__ A, const u16* __restrict__ Bt, const u16* __restrict__ Bt2,
    void* __restrict__ Cout, const float* __restrict__ bias,
    float* __restrict__ betap, float* __restrict__ flop, int M, int N, int K)
{
  __shared__ __align__(16) u16 As[128*64];
  __shared__ __align__(16) u16 Bs[128*64];
  const int t = threadIdx.x;
  const int lane = t & 63, w = t >> 6;
  const int wr = w >> 1, wc = w & 1;
  const int g = lane >> 4, r16 = lane & 15;
  const int nwg = gridDim.x * gridDim.y;
  const int bid = blockIdx.x + blockIdx.y * gridDim.x;
  const int swz = (bid & 7) * (nwg >> 3) + (bid >> 3);
  const int m0 = (swz / gridDim.x) * 128, n0 = (swz % gridDim.x) * 128;
  const bool btile = (EPI == 3) && (n0 >= 3072);
  f32x4 acc[4][4];
  #pragma unroll
  for (int i=0;i<4;++i){ f32x4 z = {0,0,0,0}; acc[i][0]=z; acc[i][1]=z; acc[i][2]=z; acc[i][3]=z; }
  const int NK = K / 64;
  const int slot_l = w*64 + lane;
  for (int kt = 0; kt < NK; ++kt){
    __syncthreads();
    #pragma unroll
    for (int j=0;j<4;++j){
      const int sl = j*256 + slot_l;
      const int row = sl >> 3, ch = sl & 7;
      const int chs = ch ^ (row & 7);        // pre-swizzled source -> swizzled linear LDS
      GLL16(A + (size_t)(m0+row)*K + kt*64 + chs*8, As + (size_t)(j*256 + w*64)*8);
      const u16* bp = btile ? (Bt2 + (size_t)row*1024 + kt*64 + chs*8)
                            : (Bt + (size_t)(n0+row)*K + kt*64 + chs*8);
      GLL16(bp, Bs + (size_t)(j*256 + w*64)*8);
    }
    __syncthreads();
    #pragma unroll
    for (int kh = 0; kh < 2; ++kh){
      s16x8 af[4], bf_[4];
      #pragma unroll
      for (int i=0;i<4;++i){
        const int arow = wr*64 + i*16 + r16;
        af[i]  = *(const s16x8*)(As + (size_t)arow*64 + (((4*kh+g) ^ (arow&7)))*8);
        const int brow = wc*64 + i*16 + r16;
        bf_[i] = *(const s16x8*)(Bs + (size_t)brow*64 + (((4*kh+g) ^ (brow&7)))*8);
      }
      #pragma unroll
      for (int mi=0;mi<4;++mi)
        #pragma unroll
        for (int ni=0;ni<4;++ni)
          acc[mi][ni] = mfma16(af[mi], bf_[ni], acc[mi][ni]);
    }
  }
  #pragma unroll
  for (int mi=0;mi<4;++mi)
    #pragma unroll
    for (int ni=0;ni<4;++ni){
      const int col = n0 + wc*64 + ni*16 + r16;
      #pragma unroll
      for (int i=0;i<4;++i){
        const int row = m0 + wr*64 + mi*16 + g*4 + i;
        float v = acc[mi][ni][i];
        if (EPI == 1){
          float x = v + bias[col];
          x = 0.5f * x * (1.0f + erff(x * 0.70710678118f));
          ((u16*)Cout)[(size_t)row*N + col] = f2bf(x);
        } else if (EPI == 2){
          ((float*)Cout)[(size_t)row*N + col] = v;
        } else { // EPI == 3
          if (col < 3072){
            ((u16*)Cout)[(size_t)(col >> 10)*8388608 + (size_t)row*1024 + (col & 1023)] = f2bf(v);
          } else {
            const int j = col - 3072;
            if (j < 8)       betap[(size_t)row*8 + j] = sigm(v);
            else if (j < 16) flop[(size_t)row*8 + (j-8)] = 0.2f * sigm(v + bias[j-8]);
          }
        }
      }
    }
}

// ---------------- causal conv(K=4) + SiLU + per-head l2norm; 16 rows/block ----------------
__global__ __launch_bounds__(256) void conv_silu_k(
    const u16* __restrict__ qraw, const u16* __restrict__ kraw, const u16* __restrict__ vraw,
    const float* __restrict__ cwq, const float* __restrict__ cwk, const float* __restrict__ cwv,
    u16* __restrict__ vdir, u16* __restrict__ qn, u16* __restrict__ kn)
{
  const int blk = blockIdx.x;           // b*128 + lt, 16 rows each
  const int b = blk >> 7, lt = blk & 127;
  const int l0 = lt * 16;
  const int t = threadIdx.x, c0 = t * 4;
  float wq[16], wk[16], wv[16];
  #pragma unroll
  for (int cc=0; cc<4; ++cc){
    float4 a = *(const float4*)(cwq + (size_t)(c0+cc)*4);
    wq[cc*4+0]=a.x; wq[cc*4+1]=a.y; wq[cc*4+2]=a.z; wq[cc*4+3]=a.w;
    float4 bq = *(const float4*)(cwk + (size_t)(c0+cc)*4);
    wk[cc*4+0]=bq.x; wk[cc*4+1]=bq.y; wk[cc*4+2]=bq.z; wk[cc*4+3]=bq.w;
    float4 c = *(const float4*)(cwv + (size_t)(c0+cc)*4);
    wv[cc*4+0]=c.x; wv[cc*4+1]=c.y; wv[cc*4+2]=c.z; wv[cc*4+3]=c.w;
  }
  float hq[3][4], hk[3][4], hv[3][4];
  #pragma unroll
  for (int i=0;i<3;++i){
    const int ls = l0 - 3 + i;
    if (ls >= 0){
      const size_t base = ((size_t)(b << 11) + ls)*1024 + c0;
      union{ ushort4 v; u16 s[4]; } xq, xk, xv;
      xq.v = *(const ushort4*)(qraw + base);
      xk.v = *(const ushort4*)(kraw + base);
      xv.v = *(const ushort4*)(vraw + base);
      #pragma unroll
      for (int cc=0;cc<4;++cc){ hq[i][cc]=bf2f(xq.s[cc]); hk[i][cc]=bf2f(xk.s[cc]); hv[i][cc]=bf2f(xv.s[cc]); }
    } else {
      #pragma unroll
      for (int cc=0;cc<4;++cc){ hq[i][cc]=0.f; hk[i][cc]=0.f; hv[i][cc]=0.f; }
    }
  }
  float cq[4], ck4[4], cv4[4], nq[4], nk[4], nv[4];
  { // load row l0
    const size_t base = ((size_t)(b << 11) + l0)*1024 + c0;
    union{ ushort4 v; u16 s[4]; } xq, xk, xv;
    xq.v = *(const ushort4*)(qraw + base);
    xk.v = *(const ushort4*)(kraw + base);
    xv.v = *(const ushort4*)(vraw + base);
    #pragma unroll
    for (int cc=0;cc<4;++cc){ cq[cc]=bf2f(xq.s[cc]); ck4[cc]=bf2f(xk.s[cc]); cv4[cc]=bf2f(xv.s[cc]); }
  }
  const int head = c0 >> 7, d0 = c0 & 127;
  for (int rr = 0; rr < 16; ++rr){
    const int l = l0 + rr;
    if (rr < 15){ // prefetch next row
      const size_t base = ((size_t)(b << 11) + l + 1)*1024 + c0;
      union{ ushort4 v; u16 s[4]; } xq, xk, xv;
      xq.v = *(const ushort4*)(qraw + base);
      xk.v = *(const ushort4*)(kraw + base);
      xv.v = *(const ushort4*)(vraw + base);
      #pragma unroll
      for (int cc=0;cc<4;++cc){ nq[cc]=bf2f(xq.s[cc]); nk[cc]=bf2f(xk.s[cc]); nv[cc]=bf2f(xv.s[cc]); }
    }
    float qa[4], ka[4], va[4];
    #pragma unroll
    for (int cc=0; cc<4; ++cc){
      qa[cc] = hq[0][cc]*wq[cc*4+0] + hq[1][cc]*wq[cc*4+1] + hq[2][cc]*wq[cc*4+2] + cq[cc]*wq[cc*4+3];
      ka[cc] = hk[0][cc]*wk[cc*4+0] + hk[1][cc]*wk[cc*4+1] + hk[2][cc]*wk[cc*4+2] + ck4[cc]*wk[cc*4+3];
      va[cc] = hv[0][cc]*wv[cc*4+0] + hv[1][cc]*wv[cc*4+1] + hv[2][cc]*wv[cc*4+2] + cv4[cc]*wv[cc*4+3];
    }
    #pragma unroll
    for (int cc=0; cc<4; ++cc){
      qa[cc] = qa[cc]*sigm(qa[cc]); ka[cc] = ka[cc]*sigm(ka[cc]); va[cc] = va[cc]*sigm(va[cc]);
    }
    const int grow = (b << 11) + l;
    ushort4 ov; ov.x=f2bf(va[0]); ov.y=f2bf(va[1]); ov.z=f2bf(va[2]); ov.w=f2bf(va[3]);
    *(ushort4*)(vdir + (size_t)grow*1024 + c0) = ov;
    float ssq = 0.f, ssk = 0.f;
    #pragma unroll
    for (int cc=0; cc<4; ++cc){ ssq += qa[cc]*qa[cc]; ssk += ka[cc]*ka[cc]; }
    #pragma unroll
    for (int m=1; m<32; m<<=1){ ssq += __shfl_xor(ssq, m, 64); ssk += __shfl_xor(ssk, m, 64); }
    const float rq = rsqrtf(ssq + 1e-6f), rk = rsqrtf(ssk + 1e-6f);
    const size_t ob = (((size_t)(b*8 + head))*2048 + l)*128 + d0;
    ushort4 oq, ok;
    oq.x=f2bf(qa[0]*rq); oq.y=f2bf(qa[1]*rq); oq.z=f2bf(qa[2]*rq); oq.w=f2bf(qa[3]*rq);
    ok.x=f2bf(ka[0]*rk); ok.y=f2bf(ka[1]*rk); ok.z=f2bf(ka[2]*rk); ok.w=f2bf(ka[3]*rk);
    *(ushort4*)(qn + ob) = oq;
    *(ushort4*)(kn + ob) = ok;
    #pragma unroll
    for (int cc=0; cc<4; ++cc){
      hq[0][cc]=hq[1][cc]; hq[1][cc]=hq[2][cc]; hq[2][cc]=cq[cc];  cq[cc]=nq[cc];
      hk[0][cc]=hk[1][cc]; hk[1][cc]=hk[2][cc]; hk[2][cc]=ck4[cc]; ck4[cc]=nk[cc];
      hv[0][cc]=hv[1][cc]; hv[1][cc]=hv[2][cc]; hv[2][cc]=cv4[cc]; cv4[cc]=nv[cc];
    }
  }
}

// ---------------- fus2: 1-wave MFMA streamer over fus1g ----------------
__global__ __launch_bounds__(64) void fus2_k(
    const u16* __restrict__ A, const u16* __restrict__ w2p, const float* __restrict__ b2,
    float* __restrict__ out)
{
  const int m0 = blockIdx.x * 16;
  const int lane = threadIdx.x, g = lane >> 4, r = lane & 15;
  f32x4 acc[2][2];
  #pragma unroll
  for (int nt=0;nt<2;++nt){ f32x4 z = {0,0,0,0}; acc[nt][0]=z; acc[nt][1]=z; }
  #pragma unroll 4
  for (int kt = 0; kt < 64; ++kt){
    s16x8 af = *(const s16x8*)(A + (size_t)(m0+r)*2048 + kt*32 + g*8);
    s16x8 b0 = *(const s16x8*)(w2p + (((size_t)kt*2 + 0)*64 + lane)*8);
    s16x8 b1 = *(const s16x8*)(w2p + (((size_t)kt*2 + 1)*64 + lane)*8);
    acc[0][kt&1] = mfma16(af, b0, acc[0][kt&1]);
    acc[1][kt&1] = mfma16(af, b1, acc[1][kt&1]);
  }
  #pragma unroll
  for (int nt=0;nt<2;++nt){
    const float bb = b2[nt*16 + r];
    #pragma unroll
    for (int i=0;i<4;++i)
      out[(size_t)(m0 + g*4 + i)*32 + nt*16 + r] = acc[nt][0][i] + acc[nt][1][i] + bb;
  }
}

// ---------------- UT transform per (b,h,chunk): T=(I-L)^-1, u=T@vb, w=T@kb ----------------
// w stored NEGATED in wpk; q A-frags stored to qpk (coalesced for the scan).
__global__ __launch_bounds__(256, 2) void ut_k(
    const u16* __restrict__ qn, const u16* __restrict__ kn,
    const u16* __restrict__ vdir, const float* __restrict__ beta,
    u16* __restrict__ alocp, u16* __restrict__ updk,
    u16* __restrict__ wpk, u16* __restrict__ knpk, u16* __restrict__ qpk)
{
  __shared__ __align__(16) char smem[39680];
  u16*  k_s = (u16*)smem;               // [32][128] XOR-swizzled (G phase only)
  float* Tm = (float*)smem;             // [32][36] f32, aliases k_s (dead after G)
  float* Gm = (float*)(smem + 8192);    // [32][33] f32 (live through T21 phase)
  float* al = (float*)(smem + 12416);   // [32][36] f32; P reuses it after packs
  float* wl = (float*)(smem + 8192);    // [32][68] f32, aliases Gm+al (u/w phase)
  u16*  knT = (u16*)(smem + 17024);     // [128 d][44] u16: knT[d][l] = kn[l][d]
  u16*  vbT = (u16*)(smem + 28288);     // [128 d][44] u16: (v*beta)^T
  float* bet = (float*)(smem + 39552);  // [32]

  const int blk = blockIdx.x;
  const int ic = blk & 63, bh = blk >> 6;
  const int b = bh >> 3, h = bh & 7;
  const int l0 = ic * 32;
  const int t = threadIdx.x;
  const int lane = t & 63, w = t >> 6;
  const int g = lane >> 4, r = lane & 15;
  const int mt = w >> 1, nt_g = w & 1;

  const size_t gqk = ((size_t)bh*2048 + l0)*128;

  { // stage k_s (B-side of G), XOR-swizzled rows
    const int row = t >> 3, sseg = t & 7;
    #pragma unroll
    for (int ss=0; ss<2; ++ss){
      const int s = sseg + ss*8;
      int4 kv = *(const int4*)(kn + gqk + (size_t)row*128 + s*8);
      *(int4*)((char*)k_s + row*256 + ((s ^ (row&7))*16)) = kv;
    }
  }
  { // stage knT / vbT via rowpair u32 writes (stride 44 -> 2-way only); bet
    const int rp = t & 15, cs = t >> 4;
    const int r0 = 2*rp, r1 = 2*rp + 1;
    union { s16x8 v; u16 u[8]; } k0, k1, v0, v1;
    k0.v = *(const s16x8*)(kn + gqk + (size_t)r0*128 + cs*8);
    k1.v = *(const s16x8*)(kn + gqk + (size_t)r1*128 + cs*8);
    v0.v = *(const s16x8*)(vdir + ((size_t)b*2048 + l0 + r0)*1024 + h*128 + cs*8);
    v1.v = *(const s16x8*)(vdir + ((size_t)b*2048 + l0 + r1)*1024 + h*128 + cs*8);
    const float be0 = beta[((size_t)b*2048 + l0 + r0)*8 + h];
    const float be1 = beta[((size_t)b*2048 + l0 + r1)*8 + h];
    if (t < 32) bet[t] = beta[((size_t)b*2048 + l0 + t)*8 + h];
    #pragma unroll
    for (int i=0;i<8;++i){
      const int d = cs*8 + i;
      *(u32*)(knT + (size_t)d*44 + r0) = (u32)k0.u[i] | ((u32)k1.u[i] << 16);
      u32 lo = f2bf(bf2f(v0.u[i]) * be0);
      u32 hi = f2bf(bf2f(v1.u[i]) * be1);
      *(u32*)(vbT + (size_t)d*44 + r0) = lo | (hi << 16);
    }
  }
  __syncthreads();

  { // G = kn@kn^T, Aloc = tril(qn@kn^T); A-frags loaded here; q frags stored to qpk
    f32x4 gacc = {0,0,0,0}, aacc = {0,0,0,0};
    #pragma unroll
    for (int kt=0; kt<4; ++kt){
      s16x8 afk = *(const s16x8*)(kn + gqk + (size_t)(mt*16+r)*128 + kt*32 + g*8);
      s16x8 afq = *(const s16x8*)(qn + gqk + (size_t)(mt*16+r)*128 + kt*32 + g*8);
      if (nt_g == 0)
        *(s16x8*)(qpk + ((((size_t)blk*2 + mt)*4 + kt)*64 + lane)*8) = afq;
      const int brow = nt_g*16 + r;
      s16x8 bfrag = *(const s16x8*)((const char*)k_s + brow*256 + (((kt*4+g) ^ (brow&7))*16));
      gacc = mfma16(afk, bfrag, gacc);
      aacc = mfma16(afq, bfrag, aacc);
    }
    #pragma unroll
    for (int i=0;i<4;++i){
      const int rr = mt*16 + g*4 + i, cc = nt_g*16 + r;
      Gm[rr*33 + cc] = gacc[i];
      al[rr*36 + cc] = (cc <= rr) ? aacc[i] : 0.f;
    }
  }
  __syncthreads();

  if (w == 0){ // blocked substitution: T11 (lanes grp0) and T22 (grp1) in parallel
    const int kk = lane & 15, grp = (lane >> 4) & 1, b0 = grp*16;
    float tc[16];
    #pragma unroll
    for (int j=0;j<16;++j)
      tc[j] = (j > kk) ? (-bet[b0+j] * Gm[(b0+j)*33 + b0+kk]) : 0.f;
    #pragma unroll
    for (int i=1;i<16;++i){
      float upd = 0.f;
      #pragma unroll
      for (int j=0;j<i;++j) upd += __shfl(tc[i], (lane & 48) + j, 64) * tc[j];
      if (kk < i) tc[i] += upd;
    }
    if (lane < 32){
      #pragma unroll
      for (int j=0;j<16;++j) Tm[(b0+j)*36 + b0+kk] = tc[j] + ((j == kk) ? 1.f : 0.f);
      if (grp == 1){
        #pragma unroll
        for (int j=0;j<16;++j) Tm[j*36 + 16 + kk] = 0.f;
      }
    }
  } else if (w == 1){ // pack Aloc A-frags
    #pragma unroll
    for (int m2=0; m2<2; ++m2){
      float4 z0 = *(const float4*)(al + (m2*16+r)*36 + g*8);
      float4 z1 = *(const float4*)(al + (m2*16+r)*36 + g*8 + 4);
      *(s16x8*)(alocp + (((size_t)blk*2 + m2)*64 + lane)*8) = pack8(z0, z1);
    }
  } else { // w==2,3: pack kn^T A-frags for the S-update
    #pragma unroll
    for (int q2=0; q2<4; ++q2){
      const int mtd = (w-2)*4 + q2;
      s16x8 vv = ld_tr(knT + (size_t)(mtd*16+r)*44 + g*8);
      *(s16x8*)(knpk + (((size_t)blk*8 + mtd)*64 + lane)*8) = vv;
    }
  }
  __syncthreads();   // al dead (aloc packed); T11/T22/zeros in Tm

  { // P = L21 @ T11  (16x16 f32), all 256 threads, one entry each -> al
    const int kP = t >> 4, cP = t & 15;
    float p = 0.f;
    #pragma unroll
    for (int m=0;m<16;++m) p += Gm[(16+kP)*33 + m] * Tm[m*36 + cP];
    al[kP*36 + cP] = -bet[16+kP] * p;
  }
  __syncthreads();

  { // T21 = T22 @ P -> Tm rows 16-31, cols 0-15
    const int rT = t >> 4, cT = t & 15;
    float s = 0.f;
    #pragma unroll
    for (int k=0;k<16;++k) s += Tm[(16+rT)*36 + 16 + k] * al[k*36 + cT];
    Tm[(16+rT)*36 + cT] = s;
  }
  __syncthreads();   // Tm complete (32x32 with zero upper block)

  { // u = T@vb (bf16 D-pair to global), w = T@kb (2-round repack via wl, NEGATED)
    float bb[8];
    #pragma unroll
    for (int i=0;i<8;++i) bb[i] = bet[g*8+i];
    s16x8 tA[2];
    #pragma unroll
    for (int m2=0; m2<2; ++m2){
      float4 x0 = *(const float4*)(Tm + (m2*16+r)*36 + g*8);
      float4 x1 = *(const float4*)(Tm + (m2*16+r)*36 + g*8 + 4);
      tA[m2] = pack8(x0, x1);
    }
    #pragma unroll
    for (int rr2=0; rr2<2; ++rr2){
      const int nt = rr2*4 + w;
      s16x8 bu   = ld_tr(vbT + (size_t)(nt*16+r)*44 + g*8);
      s16x8 braw = ld_tr(knT + (size_t)(nt*16+r)*44 + g*8);
      s16x8 bw;
      #pragma unroll
      for (int i=0;i<8;++i) bw[i] = (short)f2bf(bf2f((u16)braw[i]) * bb[i]);
      f32x4 zz = {0,0,0,0};
      f32x4 du0 = mfma16(tA[0], bu, zz);
      f32x4 du1 = mfma16(tA[1], bu, zz);
      f32x4 dw0 = mfma16(tA[0], bw, zz);
      f32x4 dw1 = mfma16(tA[1], bw, zz);
      *(s16x8*)(updk + (((size_t)blk*8 + nt)*64 + lane)*8) =
          pack8(make_float4(du0[0],du0[1],du0[2],du0[3]),
                make_float4(du1[0],du1[1],du1[2],du1[3]));
      #pragma unroll
      for (int i=0;i<4;++i){
        wl[(      g*4 + i)*68 + (nt&3)*16 + r] = -dw0[i];   // NEGATED for the scan
        wl[(16 +  g*4 + i)*68 + (nt&3)*16 + r] = -dw1[i];
      }
      __syncthreads();
      { // pack one (-w) A-frag tile per wave: (mtp, ktp)
        const int mtp = w >> 1, ktp = rr2*2 + (w & 1);
        float4 y0 = *(const float4*)(wl + (mtp*16+r)*68 + (ktp&1)*32 + g*8);
        float4 y1 = *(const float4*)(wl + (mtp*16+r)*68 + (ktp&1)*32 + g*8 + 4);
        *(s16x8*)(wpk + ((((size_t)blk*2 + mtp)*4 + ktp)*64 + lane)*8) = pack8(y0, y1);
      }
      __syncthreads();
    }
  }
}

// ---------------- chunk-serial scan, 1 wave per (b,h,dv-16 slice) ----------------
// S in registers; D->B relayout via cvt_pk + __shfl; 3-deep operand prefetch.
struct SBuf {
  s16x8 uraw;         // +u, bf16 D-pair (rows 0-15 in [0..3], 16-31 in [4..7])
  s16x8 wf[8];        // -w A-frags [mt*4+kt]
  s16x8 qf[8];        // q A-frags [mt*4+kt] (packed, coalesced)
  s16x8 a0, a1;       // Aloc A-frags
  s16x8 kf[8];        // kn^T A-frags [mtd]
};

DEVI void scan_load(SBuf& b, const u16* up, const u16* wp, const u16* qp,
                    const u16* ap, const u16* kp){
  b.uraw = *(const s16x8*)(up);
  #pragma unroll
  for (int j=0;j<8;++j) b.wf[j] = *(const s16x8*)(wp + j*512);
  #pragma unroll
  for (int j=0;j<8;++j) b.qf[j] = *(const s16x8*)(qp + j*512);
  b.a0 = *(const s16x8*)(ap);
  b.a1 = *(const s16x8*)(ap + 512);
  #pragma unroll
  for (int j=0;j<8;++j) b.kf[j] = *(const s16x8*)(kp + j*512);
}

// D-frag rows (m*16 + g*4 + ii) -> B-frag rows (g*8 + i) cross-lane relayout.
DEVI void scan_step(const SBuf& b, f32x4* Sf, u16* dptr,
                    int srcA, int srcB, bool hi, int r, int g){
  u32 pk0[8], pk1[8];
  #pragma unroll
  for (int m=0;m<8;++m){
    pk0[m] = pkbf(Sf[m][0], Sf[m][1]);
    pk1[m] = pkbf(Sf[m][2], Sf[m][3]);
  }
  s16x8 sf[4];
  #pragma unroll
  for (int kt=0;kt<4;++kt){
    u32 eA0 = __shfl(pk0[kt*2],   srcA, 64), oA0 = __shfl(pk0[kt*2+1], srcA, 64);
    u32 eA1 = __shfl(pk1[kt*2],   srcA, 64), oA1 = __shfl(pk1[kt*2+1], srcA, 64);
    u32 eB0 = __shfl(pk0[kt*2],   srcB, 64), oB0 = __shfl(pk0[kt*2+1], srcB, 64);
    u32 eB1 = __shfl(pk1[kt*2],   srcB, 64), oB1 = __shfl(pk1[kt*2+1], srcB, 64);
    union { u32 w[4]; s16x8 v; } uw;
    uw.w[0] = hi ? oA0 : eA0;
    uw.w[1] = hi ? oA1 : eA1;
    uw.w[2] = hi ? oB0 : eB0;
    uw.w[3] = hi ? oB1 : eB1;
    sf[kt] = uw.v;
  }
  f32x4 unA, unB, unA2 = {0,0,0,0}, unB2 = {0,0,0,0};
  #pragma unroll
  for (int i=0;i<4;++i){ unA[i] = bf2f((u16)b.uraw[i]); unB[i] = bf2f((u16)b.uraw[4+i]); }
  unA  = mfma16(b.wf[0], sf[0], unA);
  unA2 = mfma16(b.wf[2], sf[2], unA2);
  unB  = mfma16(b.wf[4], sf[0], unB);
  unB2 = mfma16(b.wf[6], sf[2], unB2);
  unA  = mfma16(b.wf[1], sf[1], unA);
  unA2 = mfma16(b.wf[3], sf[3], unA2);
  unB  = mfma16(b.wf[5], sf[1], unB);
  unB2 = mfma16(b.wf[7], sf[3], unB2);
  f32x4 o0 = {0,0,0,0}, o1 = {0,0,0,0};
  #pragma unroll
  for (int kt=0;kt<4;++kt){
    o0 = mfma16(b.qf[kt],   sf[kt], o0);
    o1 = mfma16(b.qf[4+kt], sf[kt], o1);
  }
  unA = unA + unA2;
  unB = unB + unB2;
  u32 a0p0 = pkbf(unA[0], unA[1]), a0p1 = pkbf(unA[2], unA[3]);
  u32 a1p0 = pkbf(unB[0], unB[1]), a1p1 = pkbf(unB[2], unB[3]);
  u32 w00 = __shfl(a0p0, srcA, 64), w10 = __shfl(a1p0, srcA, 64);
  u32 w01 = __shfl(a0p1, srcA, 64), w11 = __shfl(a1p1, srcA, 64);
  u32 w02 = __shfl(a0p0, srcB, 64), w12 = __shfl(a1p0, srcB, 64);
  u32 w03 = __shfl(a0p1, srcB, 64), w13 = __shfl(a1p1, srcB, 64);
  union { u32 w[4]; s16x8 v; } uu;
  uu.w[0] = hi ? w10 : w00;
  uu.w[1] = hi ? w11 : w01;
  uu.w[2] = hi ? w12 : w02;
  uu.w[3] = hi ? w13 : w03;
  const s16x8 uf = uu.v;
  o0 = mfma16(b.a0, uf, o0);
  o1 = mfma16(b.a1, uf, o1);
  #pragma unroll
  for (int i=0;i<4;++i){
    dptr[(size_t)(g*4+i)*128]    = f2bf(o0[i]);
    dptr[(size_t)(16+g*4+i)*128] = f2bf(o1[i]);
  }
  #pragma unroll
  for (int m=0;m<8;++m) Sf[m] = mfma16(b.kf[m], uf, Sf[m]);
}

__global__ __launch_bounds__(64, 1) void scan_k(
    const u16* __restrict__ qpk, const u16* __restrict__ wpk,
    const u16* __restrict__ updk, const u16* __restrict__ alocp,
    const u16* __restrict__ knpk, u16* __restrict__ delta)
{
  const int blk = blockIdx.x;
  const int sl = blk >> 5, bh = blk & 31;   // same-bh slices -> same XCD
  const int lane = threadIdx.x;
  const int g = lane >> 4, r = lane & 15;
  const int srcA = (g & 1)*32 + r;          // lane of source group g'=(g&1)*2
  const int srcB = srcA + 16;               // g'+1
  const bool hi = (g >= 2);
  f32x4 Sf[8];
  #pragma unroll
  for (int m=0;m<8;++m){ f32x4 z = {0,0,0,0}; Sf[m] = z; }

  const u16* upB = updk + ((size_t)bh*64*8 + sl)*512 + (size_t)lane*8;
  const u16* wpB = wpk  + (size_t)bh*64*4096 + (size_t)lane*8;
  const u16* qpB = qpk  + (size_t)bh*64*4096 + (size_t)lane*8;
  const u16* apB = alocp + (size_t)bh*64*1024 + (size_t)lane*8;
  const u16* kpB = knpk + (size_t)bh*64*4096 + (size_t)lane*8;
  u16*       dB  = delta + (size_t)bh*2048*128 + sl*16 + r;

  #define LD(buf, n) scan_load(buf, upB + (size_t)(n)*4096, wpB + (size_t)(n)*4096, \
                               qpB + (size_t)(n)*4096, apB + (size_t)(n)*1024, \
                               kpB + (size_t)(n)*4096)
  #define ST(buf, n) scan_step(buf, Sf, dB + (size_t)(n)*4096, srcA, srcB, hi, r, g)

  SBuf A, B, C;
  LD(A, 0); LD(B, 1);
  for (int ic = 0; ic < 63; ic += 3){
    LD(C, ic+2);
    ST(A, ic);
    if (ic + 3 < 64) LD(A, ic+3);
    ST(B, ic+1);
    if (ic + 4 < 64) LD(B, ic+4);
    ST(C, ic+2);
  }
  ST(A, 63);
  #undef LD
  #undef ST
}

// ---------------- FIR(3,31) + gating + double RMS -> o_final bf16 ----------------
__global__ __launch_bounds__(256) void fuse_k(
    const u16* __restrict__ vdir, const u16* __restrict__ delta,
    const float* __restrict__ fusv, const float* __restrict__ flo,
    const float* __restrict__ fsw, const float* __restrict__ flw,
    const float* __restrict__ wpf, const float* __restrict__ wno,
    u16* __restrict__ ofin)
{
  __shared__ float fl_t[31][128];   // transposed long-FIR weights for head h
  const int blk = blockIdx.x;
  const int lt = blk & 31, h = (blk >> 5) & 7, b = blk >> 8;
  const int t = threadIdx.x;
  const int w = t >> 6, lane = t & 63;
  const int d0 = lane * 2;
  const int l0 = lt*64 + w*16;          // this warp's first output row
  for (int j = t; j < 3968; j += 256){
    const int d = j / 31, i = j - d*31;
    fl_t[i][d] = flw[(size_t)h*3968 + j];
  }
  __syncthreads();
  float wlo[46], whi[46];
  #pragma unroll
  for (int j = 0; j < 46; ++j){
    const int ls = l0 - 30 + j;
    u32 x = 0;
    if (ls >= 0) x = *(const u32*)(vdir + ((size_t)b*2048 + ls)*1024 + h*128 + d0);
    wlo[j] = bf2f((u16)(x & 0xffffu));
    whi[j] = bf2f((u16)(x >> 16));
  }
  float lg0[16], lg1[16];
  #pragma unroll
  for (int rr = 0; rr < 16; ++rr){ lg0[rr] = 0.f; lg1[rr] = 0.f; }
  #pragma unroll
  for (int i = 0; i < 31; ++i){
    const float2 wv = *(const float2*)&fl_t[i][d0];
    #pragma unroll
    for (int rr = 0; rr < 16; ++rr){
      lg0[rr] += wlo[rr + i] * wv.x;
      lg1[rr] += whi[rr + i] * wv.y;
    }
  }
  const float wp0 = wpf[d0], wp1 = wpf[d0+1];
  const float wn0 = wno[d0], wn1 = wno[d0+1];
  float fs0[3], fs1[3];
  #pragma unroll
  for (int i=0;i<3;++i){
    fs0[i] = fsw[((size_t)h*128 + d0)*3 + i];
    fs1[i] = fsw[((size_t)h*128 + d0 + 1)*3 + i];
  }
  #pragma unroll
  for (int rr = 0; rr < 16; ++rr){
    const int l = l0 + rr;
    const float* fr = fusv + ((size_t)b*2048 + l)*32 + h*4;   // warp-uniform
    const float f0=fr[0], f1=fr[1], f2=fr[2], f3=fr[3];
    const float flv = flo[((size_t)b*2048 + l)*8 + h];
    const float p = sigm(f3) * (1.f - flv);
    const float mx = fmaxf(f0, fmaxf(f1, f2));
    const float e0 = __expf(f0-mx), e1 = __expf(f1-mx), e2 = __expf(f2-mx);
    const float inv = (1.f - p) / (e0 + e1 + e2);
    const float c0 = e0*inv, c1 = e1*inv, c2 = e2*inv;
    const float sh0 = wlo[rr+28]*fs0[0] + wlo[rr+29]*fs0[1] + wlo[rr+30]*fs0[2];
    const float sh1 = whi[rr+28]*fs1[0] + whi[rr+29]*fs1[1] + whi[rr+30]*fs1[2];
    const u32 dl2 = *(const u32*)(delta + (((size_t)(b*8 + h))*2048 + l)*128 + d0);
    const float dlx = bf2f((u16)(dl2 & 0xffffu)), dly = bf2f((u16)(dl2 >> 16));
    float o0 = c0*sh0 + c1*lg0[rr] + c2*dlx + p*wlo[rr+30];
    float o1 = c0*sh1 + c1*lg1[rr] + c2*dly + p*whi[rr+30];
    const float b0 = o0*wp0, b1 = o1*wp1;
    float ss = o0*o0 + o1*o1;
    float tt = b0*b0 + b1*b1;
    #pragma unroll
    for (int m=1; m<64; m<<=1){
      ss += __shfl_xor(ss, m, 64);
      tt += __shfl_xor(tt, m, 64);
    }
    const float r1 = rsqrtf(ss * (1.f/128.f) + 1e-5f);
    const float r2 = rsqrtf(r1*r1*tt * (1.f/128.f) + 1e-5f);
    const u32 h0 = f2bf(o0*r1*wp0*r2*wn0), h1 = f2bf(o1*r1*wp1*r2*wn1);
    *(u32*)(ofin + ((size_t)b*2048 + l)*1024 + h*128 + d0) = h0 | (h1 << 16);
  }
}

// ---------------- workspace layout (lifetime-aliased) ----------------
constexpr size_t OFF_HSB  = 0;          // hsb until fus1 GEMM; then qpk (16.7MB)
constexpr size_t OFF_WQT  = 16777216;   // wq/wk/wv transposed, contiguous (N=3072 B)
constexpr size_t OFF_WKT  = 18874368;
constexpr size_t OFF_WVT  = 20971520;
constexpr size_t OFF_W1T  = 23068672;
constexpr size_t OFF_WOT  = 27262976;
constexpr size_t OFF_QRAW = 29360128;   // q/k/v raw; after conv: fus1g; after fus2: delta
constexpr size_t OFF_KRAW = 46137344;
constexpr size_t OFF_VRAW = 62914560;   // after conv: wpk
constexpr size_t OFF_FUSV = 79691776;
constexpr size_t OFF_BETA = 80740352;
constexpr size_t OFF_FLO  = 81002496;
constexpr size_t OFF_VDIR = 81264640;   // bf16
constexpr size_t OFF_W2P  = 98041856;   // W2 B-frags, 128KB
constexpr size_t OFF_WBFT = 98205696;   // [Wb|Wfl]^T padded [128][1024] bf16, 256KB
constexpr size_t OFF_QN   = 114819072;
constexpr size_t OFF_KN   = 131596288;
constexpr size_t OFF_ALOC = 148373504;
constexpr size_t OFF_UPDK = 152567808;  // bf16; after scan: ofin
constexpr size_t OFF_KNPK = 186122240;  // end: 202899456

extern "C" void kernel_launch(void* const* d_in, const int* in_sizes, int n_in,
                              void* d_out, int out_size, void* d_ws, size_t ws_size,
                              hipStream_t stream)
{
  const float* hs   = (const float*)d_in[0];
  const float* Wq   = (const float*)d_in[1];
  const float* Wk   = (const float*)d_in[2];
  const float* Wv   = (const float*)d_in[3];
  const float* Wb   = (const float*)d_in[4];
  const float* cq   = (const float*)d_in[5];
  const float* ck   = (const float*)d_in[6];
  const float* cv   = (const float*)d_in[7];
  const float* firs = (const float*)d_in[8];
  const float* firl = (const float*)d_in[9];
  const float* flW  = (const float*)d_in[10];
  const float* flb  = (const float*)d_in[11];
  const float* W1   = (const float*)d_in[12];
  const float* b1   = (const float*)d_in[13];
  const float* W2   = (const float*)d_in[14];
  const float* b2   = (const float*)d_in[15];
  const float* npf  = (const float*)d_in[16];
  const float* now  = (const float*)d_in[17];
  const float* Wo   = (const float*)d_in[18];

  char* ws = (char*)d_ws;
  u16*   hsb   = (u16*)(ws + OFF_HSB);
  u16*   wqT   = (u16*)(ws + OFF_WQT);
  u16*   wkT   = (u16*)(ws + OFF_WKT);
  u16*   wvT   = (u16*)(ws + OFF_WVT);
  u16*   w1T   = (u16*)(ws + OFF_W1T);
  u16*   woT   = (u16*)(ws + OFF_WOT);
  u16*   qraw  = (u16*)(ws + OFF_QRAW);
  u16*   kraw  = (u16*)(ws + OFF_KRAW);
  u16*   vraw  = (u16*)(ws + OFF_VRAW);
  u16*   fus1g = (u16*)(ws + OFF_QRAW);   // alias (qraw/kraw dead after conv)
  float* fusv  = (float*)(ws + OFF_FUSV);
  float* beta  = (float*)(ws + OFF_BETA);
  float* flo   = (float*)(ws + OFF_FLO);
  u16*   vdir  = (u16*)(ws + OFF_VDIR);   // bf16
  u16*   w2p   = (u16*)(ws + OFF_W2P);
  u16*   wbfT  = (u16*)(ws + OFF_WBFT);
  u16*   qn    = (u16*)(ws + OFF_QN);
  u16*   kn    = (u16*)(ws + OFF_KN);
  u16*   alocp = (u16*)(ws + OFF_ALOC);
  u16*   updk  = (u16*)(ws + OFF_UPDK);   // bf16
  u16*   wpk   = (u16*)(ws + OFF_VRAW);   // alias (vraw dead after conv); holds -w
  u16*   knpk  = (u16*)(ws + OFF_KNPK);
  u16*   qpk   = (u16*)(ws + OFF_HSB);    // alias (hsb dead after fus1 GEMM)
  u16*   delta = (u16*)(ws + OFF_QRAW);   // alias (fus1g dead after fus2), bf16
  u16*   ofin  = (u16*)(ws + OFF_UPDK);   // alias (updk dead after scan)

  // 1. merged prep: weight transposes + w2pack + wbfT + hs->bf16 (one launch)
  prep_k<<<14480, 256, 0, stream>>>(Wq, Wk, Wv, W1, Wo, W2, Wb, flW, hs,
                                    wqT, wkT, wvT, w1T, woT, w2p, wbfT, hsb);
  // 2. merged QKV + beta/floor projection (N=3200; last tile reads wbfT)
  gemm_bt<3><<<dim3(25,64), 256, 0, stream>>>(hsb, wqT, wbfT, qraw, flb,
                                              beta, flo, 8192, 3200, 1024);
  // 3. conv + silu + l2norm (16 rows/block, register history)
  conv_silu_k<<<512, 256, 0, stream>>>(qraw, kraw, vraw, cq, ck, cv, vdir, qn, kn);
  // 4. fusion MLP layer 1 (+bias, gelu) — last reader of hsb
  gemm_bt<1><<<dim3(16,64), 256, 0, stream>>>(hsb, w1T, nullptr, fus1g, b1,
                                              nullptr, nullptr, 8192, 2048, 1024);
  // 5. fusion MLP layer 2 (MFMA streamer)
  fus2_k<<<512, 64, 0, stream>>>(fus1g, w2p, b2, fusv);
  // 6. UT transform + fragment packing (w negated; q packed to qpk over dead hsb)
  ut_k<<<2048, 256, 0, stream>>>(qn, kn, vdir, beta, alocp, updk, wpk, knpk, qpk);
  // 7. chunk-serial scan (256 x 1-wave, 3-deep prefetch)
  scan_k<<<256, 64, 0, stream>>>(qpk, wpk, updk, alocp, knpk, delta);
  // 8. FIR + gating + double RMS (register-window FIR)
  fuse_k<<<1024, 256, 0, stream>>>(vdir, delta, fusv, flo, firs, firl, npf, now, ofin);
  // 9. output projection
  gemm_bt<2><<<dim3(8,64), 256, 0, stream>>>(ofin, woT, nullptr, d_out, nullptr,
                                             nullptr, nullptr, 8192, 1024, 1024);
}

// Round 17
// 329.131 us; speedup vs baseline: 1.0143x; 1.0143x over previous
//
// DeltaNet forward, MI355X/gfx950. Round 17: revert r16's beta/floor GEMM fold
// (per-iter B-pointer branch broke staging addr scheduling: QKV 58->73 µs).
// = r15 structure + hs->bf16 folded into prep_k. r15 = 331 µs.
#include <hip/hip_runtime.h>
#include <hip/hip_bf16.h>
#include <cstdint>
#include <cstddef>

#define DEVI static __device__ __forceinline__

typedef __attribute__((ext_vector_type(4))) float f32x4;
typedef __attribute__((ext_vector_type(8))) short s16x8;
typedef unsigned short u16;
typedef unsigned int u32;

DEVI float bf2f(u16 u){ u32 x = ((u32)u) << 16; float f; __builtin_memcpy(&f, &x, 4); return f; }
DEVI u16 f2bf(float f){ u32 x; __builtin_memcpy(&x, &f, 4); u32 r = x + 0x7fffu + ((x >> 16) & 1u); return (u16)(r >> 16); }
DEVI float sigm(float x){ return 1.0f / (1.0f + __expf(-x)); }
DEVI f32x4 mfma16(s16x8 a, s16x8 b, f32x4 c){ return __builtin_amdgcn_mfma_f32_16x16x32_bf16(a, b, c, 0, 0, 0); }
DEVI s16x8 pack8(float4 a, float4 b){
  s16x8 v;
  v[0]=(short)f2bf(a.x); v[1]=(short)f2bf(a.y); v[2]=(short)f2bf(a.z); v[3]=(short)f2bf(a.w);
  v[4]=(short)f2bf(b.x); v[5]=(short)f2bf(b.y); v[6]=(short)f2bf(b.z); v[7]=(short)f2bf(b.w);
  return v;
}
// packed bf16x2 from two f32 (RNE) — no builtin on gfx950, single VOP3 via asm
DEVI u32 pkbf(float lo, float hi){
  u32 d; asm("v_cvt_pk_bf16_f32 %0, %1, %2" : "=v"(d) : "v"(lo), "v"(hi));
  return d;
}
// two 8B-aligned LDS reads (stride-44 u16 rows are 8B- but not 16B-aligned)
DEVI s16x8 ld_tr(const u16* p){
  short4 a = *(const short4*)p;
  short4 b = *(const short4*)(p + 4);
  s16x8 v; v[0]=a.x; v[1]=a.y; v[2]=a.z; v[3]=a.w; v[4]=b.x; v[5]=b.y; v[6]=b.z; v[7]=b.w;
  return v;
}

// async global->LDS, 16B per lane; LDS dest is wave-uniform base + lane*16.
#define GLL16(gp, lp) __builtin_amdgcn_global_load_lds( \
    (const __attribute__((address_space(1))) void*)(gp), \
    (__attribute__((address_space(3))) void*)(lp), 16, 0, 0)

// ---------------- merged prep: transposes + w2pack + wbpack + hs->bf16 ----------------
// blocks [0,3072) Wq/Wk/Wv, [3072,5120) W1, [5120,6144) Wo,
// [6144,6272) w2pack, [6272,6304) wbpack, [6304,14496) hs -> bf16.
DEVI void transpose_tile(const float* src, u16* dst, int K, int N,
                         int n0, int k0, int t){
  __shared__ float tile[32][33];
  const int cc = t & 31, rb = t >> 5;
  #pragma unroll
  for (int it = 0; it < 4; ++it){ int rr = rb + it*8; tile[rr][cc] = src[(size_t)(k0+rr)*N + n0 + cc]; }
  __syncthreads();
  #pragma unroll
  for (int it = 0; it < 4; ++it){ int rr = rb + it*8; dst[(size_t)(n0+rr)*K + k0 + cc] = f2bf(tile[cc][rr]); }
}

__global__ __launch_bounds__(256) void prep_k(
    const float* __restrict__ Wq, const float* __restrict__ Wk, const float* __restrict__ Wv,
    const float* __restrict__ W1, const float* __restrict__ Wo,
    const float* __restrict__ W2, const float* __restrict__ Wb, const float* __restrict__ Wfl,
    const float* __restrict__ hs,
    u16* __restrict__ wqT, u16* __restrict__ wkT, u16* __restrict__ wvT,
    u16* __restrict__ w1T, u16* __restrict__ woT,
    u16* __restrict__ w2p, u16* __restrict__ wbp, u16* __restrict__ hsb)
{
  const int blk = blockIdx.x, t = threadIdx.x;
  if (blk < 3072){
    const int which = blk >> 10, tile = blk & 1023;
    const float* src = (which == 0) ? Wq : (which == 1) ? Wk : Wv;
    u16* dst = (which == 0) ? wqT : (which == 1) ? wkT : wvT;
    transpose_tile(src, dst, 1024, 1024, (tile & 31)*32, (tile >> 5)*32, t);
  } else if (blk < 5120){
    const int tile = blk - 3072;
    transpose_tile(W1, w1T, 1024, 2048, (tile & 63)*32, (tile >> 6)*32, t);
  } else if (blk < 6144){
    const int tile = blk - 5120;
    transpose_tile(Wo, woT, 1024, 1024, (tile & 31)*32, (tile >> 5)*32, t);
  } else if (blk < 6272){
    if (t < 64){
      const int i = blk - 6144, kt = i & 63, nt = i >> 6;
      const int lane = t, g = lane >> 4, r = lane & 15;
      float v[8];
      #pragma unroll
      for (int j=0;j<8;++j) v[j] = W2[(size_t)(kt*32 + g*8 + j)*32 + nt*16 + r];
      *(s16x8*)(w2p + (((size_t)kt*2 + nt)*64 + lane)*8) =
          pack8(make_float4(v[0],v[1],v[2],v[3]), make_float4(v[4],v[5],v[6],v[7]));
    }
  } else if (blk < 6304){
    if (t < 64){
      const int kt = blk - 6272;
      const int lane = t, g = lane >> 4, r = lane & 15;
      float v[8];
      #pragma unroll
      for (int j=0;j<8;++j){
        const int k = kt*32 + g*8 + j;
        v[j] = (r < 8) ? Wb[(size_t)k*8 + r] : Wfl[(size_t)k*8 + (r-8)];
      }
      *(s16x8*)(wbp + ((size_t)kt*64 + lane)*8) =
          pack8(make_float4(v[0],v[1],v[2],v[3]), make_float4(v[4],v[5],v[6],v[7]));
    }
  } else {
    const int i = (blk - 6304)*256 + t;   // i < 2097152
    float4 v = ((const float4*)hs)[i];
    ushort4 o; o.x = f2bf(v.x); o.y = f2bf(v.y); o.z = f2bf(v.z); o.w = f2bf(v.w);
    ((ushort4*)hsb)[i] = o;
  }
}

// ---------------- GEMM: A[M][K]bf16 @ Bt[N][K]bf16 -> C[M][N] ----------------
// 128x128 tile, BK=64, 4 waves (2x2), 4x4 16x16 frags/wave.
// LDS: pre-swizzled global source + XOR'd ds_read (both-sides swizzle).
// Bijective XCD block swizzle (nwg % 8 == 0 for all grids).
// EPI: 1 = +bias+gelu bf16, 2 = fp32, 3 = bf16 QKV-split.
template<int EPI>
__global__ __launch_bounds__(256, 2) void gemm_bt(
    const u16* __restrict__ A, const u16* __restrict__ Bt, void* __restrict__ Cout,
    const float* __restrict__ bias, int M, int N, int K)
{
  __shared__ __align__(16) u16 As[128*64];
  __shared__ __align__(16) u16 Bs[128*64];
  const int t = threadIdx.x;
  const int lane = t & 63, w = t >> 6;
  const int wr = w >> 1, wc = w & 1;
  const int g = lane >> 4, r16 = lane & 15;
  const int nwg = gridDim.x * gridDim.y;
  const int bid = blockIdx.x + blockIdx.y * gridDim.x;
  const int swz = (bid & 7) * (nwg >> 3) + (bid >> 3);
  const int m0 = (swz / gridDim.x) * 128, n0 = (swz % gridDim.x) * 128;
  f32x4 acc[4][4];
  #pragma unroll
  for (int i=0;i<4;++i){ f32x4 z = {0,0,0,0}; acc[i][0]=z; acc[i][1]=z; acc[i][2]=z; acc[i][3]=z; }
  const int NK = K / 64;
  const int slot_l = w*64 + lane;
  for (int kt = 0; kt < NK; ++kt){
    __syncthreads();
    #pragma unroll
    for (int j=0;j<4;++j){
      const int sl = j*256 + slot_l;
      const int row = sl >> 3, ch = sl & 7;
      const int chs = ch ^ (row & 7);        // pre-swizzled source -> swizzled linear LDS
      GLL16(A  + (size_t)(m0+row)*K + kt*64 + chs*8, As + (size_t)(j*256 + w*64)*8);
      GLL16(Bt + (size_t)(n0+row)*K + kt*64 + chs*8, Bs + (size_t)(j*256 + w*64)*8);
    }
    __syncthreads();
    #pragma unroll
    for (int kh = 0; kh < 2; ++kh){
      s16x8 af[4], bf_[4];
      #pragma unroll
      for (int i=0;i<4;++i){
        const int arow = wr*64 + i*16 + r16;
        af[i]  = *(const s16x8*)(As + (size_t)arow*64 + (((4*kh+g) ^ (arow&7)))*8);
        const int brow = wc*64 + i*16 + r16;
        bf_[i] = *(const s16x8*)(Bs + (size_t)brow*64 + (((4*kh+g) ^ (brow&7)))*8);
      }
      #pragma unroll
      for (int mi=0;mi<4;++mi)
        #pragma unroll
        for (int ni=0;ni<4;++ni)
          acc[mi][ni] = mfma16(af[mi], bf_[ni], acc[mi][ni]);
    }
  }
  #pragma unroll
  for (int mi=0;mi<4;++mi)
    #pragma unroll
    for (int ni=0;ni<4;++ni){
      const int col = n0 + wc*64 + ni*16 + r16;
      #pragma unroll
      for (int i=0;i<4;++i){
        const int row = m0 + wr*64 + mi*16 + g*4 + i;
        float v = acc[mi][ni][i];
        if (EPI == 1){
          float x = v + bias[col];
          x = 0.5f * x * (1.0f + erff(x * 0.70710678118f));
          ((u16*)Cout)[(size_t)row*N + col] = f2bf(x);
        } else if (EPI == 2){
          ((float*)Cout)[(size_t)row*N + col] = v;
        } else { // EPI == 3
          ((u16*)Cout)[(size_t)(col >> 10)*8388608 + (size_t)row*1024 + (col & 1023)] = f2bf(v);
        }
      }
    }
}

// ---------------- beta/floor: 1-wave MFMA streamer over hsb ----------------
__global__ __launch_bounds__(64) void beta_floor_k(
    const u16* __restrict__ hsb, const u16* __restrict__ wbp, const float* __restrict__ flb,
    float* __restrict__ beta, float* __restrict__ flo)
{
  const int m0 = blockIdx.x * 16;
  const int lane = threadIdx.x, g = lane >> 4, r = lane & 15;
  f32x4 acc0 = {0,0,0,0}, acc1 = {0,0,0,0};
  #pragma unroll 4
  for (int kt = 0; kt < 32; kt += 2){
    s16x8 a0 = *(const s16x8*)(hsb + (size_t)(m0+r)*1024 + kt*32 + g*8);
    s16x8 b0 = *(const s16x8*)(wbp + ((size_t)kt*64 + lane)*8);
    s16x8 a1 = *(const s16x8*)(hsb + (size_t)(m0+r)*1024 + (kt+1)*32 + g*8);
    s16x8 b1 = *(const s16x8*)(wbp + ((size_t)(kt+1)*64 + lane)*8);
    acc0 = mfma16(a0, b0, acc0);
    acc1 = mfma16(a1, b1, acc1);
  }
  const float fb = (r >= 8) ? flb[r-8] : 0.f;
  #pragma unroll
  for (int i=0;i<4;++i){
    const int row = m0 + g*4 + i;
    const float v = acc0[i] + acc1[i];
    if (r < 8) beta[(size_t)row*8 + r] = sigm(v);
    else       flo [(size_t)row*8 + (r-8)] = 0.2f * sigm(v + fb);
  }
}

// ---------------- causal conv(K=4) + SiLU + per-head l2norm; 16 rows/block ----------------
__global__ __launch_bounds__(256) void conv_silu_k(
    const u16* __restrict__ qraw, const u16* __restrict__ kraw, const u16* __restrict__ vraw,
    const float* __restrict__ cwq, const float* __restrict__ cwk, const float* __restrict__ cwv,
    u16* __restrict__ vdir, u16* __restrict__ qn, u16* __restrict__ kn)
{
  const int blk = blockIdx.x;           // b*128 + lt, 16 rows each
  const int b = blk >> 7, lt = blk & 127;
  const int l0 = lt * 16;
  const int t = threadIdx.x, c0 = t * 4;
  float wq[16], wk[16], wv[16];
  #pragma unroll
  for (int cc=0; cc<4; ++cc){
    float4 a = *(const float4*)(cwq + (size_t)(c0+cc)*4);
    wq[cc*4+0]=a.x; wq[cc*4+1]=a.y; wq[cc*4+2]=a.z; wq[cc*4+3]=a.w;
    float4 bq = *(const float4*)(cwk + (size_t)(c0+cc)*4);
    wk[cc*4+0]=bq.x; wk[cc*4+1]=bq.y; wk[cc*4+2]=bq.z; wk[cc*4+3]=bq.w;
    float4 c = *(const float4*)(cwv + (size_t)(c0+cc)*4);
    wv[cc*4+0]=c.x; wv[cc*4+1]=c.y; wv[cc*4+2]=c.z; wv[cc*4+3]=c.w;
  }
  float hq[3][4], hk[3][4], hv[3][4];
  #pragma unroll
  for (int i=0;i<3;++i){
    const int ls = l0 - 3 + i;
    if (ls >= 0){
      const size_t base = ((size_t)(b << 11) + ls)*1024 + c0;
      union{ ushort4 v; u16 s[4]; } xq, xk, xv;
      xq.v = *(const ushort4*)(qraw + base);
      xk.v = *(const ushort4*)(kraw + base);
      xv.v = *(const ushort4*)(vraw + base);
      #pragma unroll
      for (int cc=0;cc<4;++cc){ hq[i][cc]=bf2f(xq.s[cc]); hk[i][cc]=bf2f(xk.s[cc]); hv[i][cc]=bf2f(xv.s[cc]); }
    } else {
      #pragma unroll
      for (int cc=0;cc<4;++cc){ hq[i][cc]=0.f; hk[i][cc]=0.f; hv[i][cc]=0.f; }
    }
  }
  float cq[4], ck4[4], cv4[4], nq[4], nk[4], nv[4];
  { // load row l0
    const size_t base = ((size_t)(b << 11) + l0)*1024 + c0;
    union{ ushort4 v; u16 s[4]; } xq, xk, xv;
    xq.v = *(const ushort4*)(qraw + base);
    xk.v = *(const ushort4*)(kraw + base);
    xv.v = *(const ushort4*)(vraw + base);
    #pragma unroll
    for (int cc=0;cc<4;++cc){ cq[cc]=bf2f(xq.s[cc]); ck4[cc]=bf2f(xk.s[cc]); cv4[cc]=bf2f(xv.s[cc]); }
  }
  const int head = c0 >> 7, d0 = c0 & 127;
  for (int rr = 0; rr < 16; ++rr){
    const int l = l0 + rr;
    if (rr < 15){ // prefetch next row
      const size_t base = ((size_t)(b << 11) + l + 1)*1024 + c0;
      union{ ushort4 v; u16 s[4]; } xq, xk, xv;
      xq.v = *(const ushort4*)(qraw + base);
      xk.v = *(const ushort4*)(kraw + base);
      xv.v = *(const ushort4*)(vraw + base);
      #pragma unroll
      for (int cc=0;cc<4;++cc){ nq[cc]=bf2f(xq.s[cc]); nk[cc]=bf2f(xk.s[cc]); nv[cc]=bf2f(xv.s[cc]); }
    }
    float qa[4], ka[4], va[4];
    #pragma unroll
    for (int cc=0; cc<4; ++cc){
      qa[cc] = hq[0][cc]*wq[cc*4+0] + hq[1][cc]*wq[cc*4+1] + hq[2][cc]*wq[cc*4+2] + cq[cc]*wq[cc*4+3];
      ka[cc] = hk[0][cc]*wk[cc*4+0] + hk[1][cc]*wk[cc*4+1] + hk[2][cc]*wk[cc*4+2] + ck4[cc]*wk[cc*4+3];
      va[cc] = hv[0][cc]*wv[cc*4+0] + hv[1][cc]*wv[cc*4+1] + hv[2][cc]*wv[cc*4+2] + cv4[cc]*wv[cc*4+3];
    }
    #pragma unroll
    for (int cc=0; cc<4; ++cc){
      qa[cc] = qa[cc]*sigm(qa[cc]); ka[cc] = ka[cc]*sigm(ka[cc]); va[cc] = va[cc]*sigm(va[cc]);
    }
    const int grow = (b << 11) + l;
    ushort4 ov; ov.x=f2bf(va[0]); ov.y=f2bf(va[1]); ov.z=f2bf(va[2]); ov.w=f2bf(va[3]);
    *(ushort4*)(vdir + (size_t)grow*1024 + c0) = ov;
    float ssq = 0.f, ssk = 0.f;
    #pragma unroll
    for (int cc=0; cc<4; ++cc){ ssq += qa[cc]*qa[cc]; ssk += ka[cc]*ka[cc]; }
    #pragma unroll
    for (int m=1; m<32; m<<=1){ ssq += __shfl_xor(ssq, m, 64); ssk += __shfl_xor(ssk, m, 64); }
    const float rq = rsqrtf(ssq + 1e-6f), rk = rsqrtf(ssk + 1e-6f);
    const size_t ob = (((size_t)(b*8 + head))*2048 + l)*128 + d0;
    ushort4 oq, ok;
    oq.x=f2bf(qa[0]*rq); oq.y=f2bf(qa[1]*rq); oq.z=f2bf(qa[2]*rq); oq.w=f2bf(qa[3]*rq);
    ok.x=f2bf(ka[0]*rk); ok.y=f2bf(ka[1]*rk); ok.z=f2bf(ka[2]*rk); ok.w=f2bf(ka[3]*rk);
    *(ushort4*)(qn + ob) = oq;
    *(ushort4*)(kn + ob) = ok;
    #pragma unroll
    for (int cc=0; cc<4; ++cc){
      hq[0][cc]=hq[1][cc]; hq[1][cc]=hq[2][cc]; hq[2][cc]=cq[cc];  cq[cc]=nq[cc];
      hk[0][cc]=hk[1][cc]; hk[1][cc]=hk[2][cc]; hk[2][cc]=ck4[cc]; ck4[cc]=nk[cc];
      hv[0][cc]=hv[1][cc]; hv[1][cc]=hv[2][cc]; hv[2][cc]=cv4[cc]; cv4[cc]=nv[cc];
    }
  }
}

// ---------------- fus2: 1-wave MFMA streamer over fus1g ----------------
__global__ __launch_bounds__(64) void fus2_k(
    const u16* __restrict__ A, const u16* __restrict__ w2p, const float* __restrict__ b2,
    float* __restrict__ out)
{
  const int m0 = blockIdx.x * 16;
  const int lane = threadIdx.x, g = lane >> 4, r = lane & 15;
  f32x4 acc[2][2];
  #pragma unroll
  for (int nt=0;nt<2;++nt){ f32x4 z = {0,0,0,0}; acc[nt][0]=z; acc[nt][1]=z; }
  #pragma unroll 4
  for (int kt = 0; kt < 64; ++kt){
    s16x8 af = *(const s16x8*)(A + (size_t)(m0+r)*2048 + kt*32 + g*8);
    s16x8 b0 = *(const s16x8*)(w2p + (((size_t)kt*2 + 0)*64 + lane)*8);
    s16x8 b1 = *(const s16x8*)(w2p + (((size_t)kt*2 + 1)*64 + lane)*8);
    acc[0][kt&1] = mfma16(af, b0, acc[0][kt&1]);
    acc[1][kt&1] = mfma16(af, b1, acc[1][kt&1]);
  }
  #pragma unroll
  for (int nt=0;nt<2;++nt){
    const float bb = b2[nt*16 + r];
    #pragma unroll
    for (int i=0;i<4;++i)
      out[(size_t)(m0 + g*4 + i)*32 + nt*16 + r] = acc[nt][0][i] + acc[nt][1][i] + bb;
  }
}

// ---------------- UT transform per (b,h,chunk): T=(I-L)^-1, u=T@vb, w=T@kb ----------------
// w stored NEGATED in wpk; q A-frags stored to qpk (coalesced for the scan).
__global__ __launch_bounds__(256, 2) void ut_k(
    const u16* __restrict__ qn, const u16* __restrict__ kn,
    const u16* __restrict__ vdir, const float* __restrict__ beta,
    u16* __restrict__ alocp, u16* __restrict__ updk,
    u16* __restrict__ wpk, u16* __restrict__ knpk, u16* __restrict__ qpk)
{
  __shared__ __align__(16) char smem[39680];
  u16*  k_s = (u16*)smem;               // [32][128] XOR-swizzled (G phase only)
  float* Tm = (float*)smem;             // [32][36] f32, aliases k_s (dead after G)
  float* Gm = (float*)(smem + 8192);    // [32][33] f32 (live through T21 phase)
  float* al = (float*)(smem + 12416);   // [32][36] f32; P reuses it after packs
  float* wl = (float*)(smem + 8192);    // [32][68] f32, aliases Gm+al (u/w phase)
  u16*  knT = (u16*)(smem + 17024);     // [128 d][44] u16: knT[d][l] = kn[l][d]
  u16*  vbT = (u16*)(smem + 28288);     // [128 d][44] u16: (v*beta)^T
  float* bet = (float*)(smem + 39552);  // [32]

  const int blk = blockIdx.x;
  const int ic = blk & 63, bh = blk >> 6;
  const int b = bh >> 3, h = bh & 7;
  const int l0 = ic * 32;
  const int t = threadIdx.x;
  const int lane = t & 63, w = t >> 6;
  const int g = lane >> 4, r = lane & 15;
  const int mt = w >> 1, nt_g = w & 1;

  const size_t gqk = ((size_t)bh*2048 + l0)*128;

  { // stage k_s (B-side of G), XOR-swizzled rows
    const int row = t >> 3, sseg = t & 7;
    #pragma unroll
    for (int ss=0; ss<2; ++ss){
      const int s = sseg + ss*8;
      int4 kv = *(const int4*)(kn + gqk + (size_t)row*128 + s*8);
      *(int4*)((char*)k_s + row*256 + ((s ^ (row&7))*16)) = kv;
    }
  }
  { // stage knT / vbT via rowpair u32 writes (stride 44 -> 2-way only); bet
    const int rp = t & 15, cs = t >> 4;
    const int r0 = 2*rp, r1 = 2*rp + 1;
    union { s16x8 v; u16 u[8]; } k0, k1, v0, v1;
    k0.v = *(const s16x8*)(kn + gqk + (size_t)r0*128 + cs*8);
    k1.v = *(const s16x8*)(kn + gqk + (size_t)r1*128 + cs*8);
    v0.v = *(const s16x8*)(vdir + ((size_t)b*2048 + l0 + r0)*1024 + h*128 + cs*8);
    v1.v = *(const s16x8*)(vdir + ((size_t)b*2048 + l0 + r1)*1024 + h*128 + cs*8);
    const float be0 = beta[((size_t)b*2048 + l0 + r0)*8 + h];
    const float be1 = beta[((size_t)b*2048 + l0 + r1)*8 + h];
    if (t < 32) bet[t] = beta[((size_t)b*2048 + l0 + t)*8 + h];
    #pragma unroll
    for (int i=0;i<8;++i){
      const int d = cs*8 + i;
      *(u32*)(knT + (size_t)d*44 + r0) = (u32)k0.u[i] | ((u32)k1.u[i] << 16);
      u32 lo = f2bf(bf2f(v0.u[i]) * be0);
      u32 hi = f2bf(bf2f(v1.u[i]) * be1);
      *(u32*)(vbT + (size_t)d*44 + r0) = lo | (hi << 16);
    }
  }
  __syncthreads();

  { // G = kn@kn^T, Aloc = tril(qn@kn^T); A-frags loaded here; q frags stored to qpk
    f32x4 gacc = {0,0,0,0}, aacc = {0,0,0,0};
    #pragma unroll
    for (int kt=0; kt<4; ++kt){
      s16x8 afk = *(const s16x8*)(kn + gqk + (size_t)(mt*16+r)*128 + kt*32 + g*8);
      s16x8 afq = *(const s16x8*)(qn + gqk + (size_t)(mt*16+r)*128 + kt*32 + g*8);
      if (nt_g == 0)
        *(s16x8*)(qpk + ((((size_t)blk*2 + mt)*4 + kt)*64 + lane)*8) = afq;
      const int brow = nt_g*16 + r;
      s16x8 bfrag = *(const s16x8*)((const char*)k_s + brow*256 + (((kt*4+g) ^ (brow&7))*16));
      gacc = mfma16(afk, bfrag, gacc);
      aacc = mfma16(afq, bfrag, aacc);
    }
    #pragma unroll
    for (int i=0;i<4;++i){
      const int rr = mt*16 + g*4 + i, cc = nt_g*16 + r;
      Gm[rr*33 + cc] = gacc[i];
      al[rr*36 + cc] = (cc <= rr) ? aacc[i] : 0.f;
    }
  }
  __syncthreads();

  if (w == 0){ // blocked substitution: T11 (lanes grp0) and T22 (grp1) in parallel
    const int kk = lane & 15, grp = (lane >> 4) & 1, b0 = grp*16;
    float tc[16];
    #pragma unroll
    for (int j=0;j<16;++j)
      tc[j] = (j > kk) ? (-bet[b0+j] * Gm[(b0+j)*33 + b0+kk]) : 0.f;
    #pragma unroll
    for (int i=1;i<16;++i){
      float upd = 0.f;
      #pragma unroll
      for (int j=0;j<i;++j) upd += __shfl(tc[i], (lane & 48) + j, 64) * tc[j];
      if (kk < i) tc[i] += upd;
    }
    if (lane < 32){
      #pragma unroll
      for (int j=0;j<16;++j) Tm[(b0+j)*36 + b0+kk] = tc[j] + ((j == kk) ? 1.f : 0.f);
      if (grp == 1){
        #pragma unroll
        for (int j=0;j<16;++j) Tm[j*36 + 16 + kk] = 0.f;
      }
    }
  } else if (w == 1){ // pack Aloc A-frags
    #pragma unroll
    for (int m2=0; m2<2; ++m2){
      float4 z0 = *(const float4*)(al + (m2*16+r)*36 + g*8);
      float4 z1 = *(const float4*)(al + (m2*16+r)*36 + g*8 + 4);
      *(s16x8*)(alocp + (((size_t)blk*2 + m2)*64 + lane)*8) = pack8(z0, z1);
    }
  } else { // w==2,3: pack kn^T A-frags for the S-update
    #pragma unroll
    for (int q2=0; q2<4; ++q2){
      const int mtd = (w-2)*4 + q2;
      s16x8 vv = ld_tr(knT + (size_t)(mtd*16+r)*44 + g*8);
      *(s16x8*)(knpk + (((size_t)blk*8 + mtd)*64 + lane)*8) = vv;
    }
  }
  __syncthreads();   // al dead (aloc packed); T11/T22/zeros in Tm

  { // P = L21 @ T11  (16x16 f32), all 256 threads, one entry each -> al
    const int kP = t >> 4, cP = t & 15;
    float p = 0.f;
    #pragma unroll
    for (int m=0;m<16;++m) p += Gm[(16+kP)*33 + m] * Tm[m*36 + cP];
    al[kP*36 + cP] = -bet[16+kP] * p;
  }
  __syncthreads();

  { // T21 = T22 @ P -> Tm rows 16-31, cols 0-15
    const int rT = t >> 4, cT = t & 15;
    float s = 0.f;
    #pragma unroll
    for (int k=0;k<16;++k) s += Tm[(16+rT)*36 + 16 + k] * al[k*36 + cT];
    Tm[(16+rT)*36 + cT] = s;
  }
  __syncthreads();   // Tm complete (32x32 with zero upper block)

  { // u = T@vb (bf16 D-pair to global), w = T@kb (2-round repack via wl, NEGATED)
    float bb[8];
    #pragma unroll
    for (int i=0;i<8;++i) bb[i] = bet[g*8+i];
    s16x8 tA[2];
    #pragma unroll
    for (int m2=0; m2<2; ++m2){
      float4 x0 = *(const float4*)(Tm + (m2*16+r)*36 + g*8);
      float4 x1 = *(const float4*)(Tm + (m2*16+r)*36 + g*8 + 4);
      tA[m2] = pack8(x0, x1);
    }
    #pragma unroll
    for (int rr2=0; rr2<2; ++rr2){
      const int nt = rr2*4 + w;
      s16x8 bu   = ld_tr(vbT + (size_t)(nt*16+r)*44 + g*8);
      s16x8 braw = ld_tr(knT + (size_t)(nt*16+r)*44 + g*8);
      s16x8 bw;
      #pragma unroll
      for (int i=0;i<8;++i) bw[i] = (short)f2bf(bf2f((u16)braw[i]) * bb[i]);
      f32x4 zz = {0,0,0,0};
      f32x4 du0 = mfma16(tA[0], bu, zz);
      f32x4 du1 = mfma16(tA[1], bu, zz);
      f32x4 dw0 = mfma16(tA[0], bw, zz);
      f32x4 dw1 = mfma16(tA[1], bw, zz);
      *(s16x8*)(updk + (((size_t)blk*8 + nt)*64 + lane)*8) =
          pack8(make_float4(du0[0],du0[1],du0[2],du0[3]),
                make_float4(du1[0],du1[1],du1[2],du1[3]));
      #pragma unroll
      for (int i=0;i<4;++i){
        wl[(      g*4 + i)*68 + (nt&3)*16 + r] = -dw0[i];   // NEGATED for the scan
        wl[(16 +  g*4 + i)*68 + (nt&3)*16 + r] = -dw1[i];
      }
      __syncthreads();
      { // pack one (-w) A-frag tile per wave: (mtp, ktp)
        const int mtp = w >> 1, ktp = rr2*2 + (w & 1);
        float4 y0 = *(const float4*)(wl + (mtp*16+r)*68 + (ktp&1)*32 + g*8);
        float4 y1 = *(const float4*)(wl + (mtp*16+r)*68 + (ktp&1)*32 + g*8 + 4);
        *(s16x8*)(wpk + ((((size_t)blk*2 + mtp)*4 + ktp)*64 + lane)*8) = pack8(y0, y1);
      }
      __syncthreads();
    }
  }
}

// ---------------- chunk-serial scan, 1 wave per (b,h,dv-16 slice) ----------------
// S in registers; D->B relayout via cvt_pk + __shfl; 3-deep operand prefetch.
struct SBuf {
  s16x8 uraw;         // +u, bf16 D-pair (rows 0-15 in [0..3], 16-31 in [4..7])
  s16x8 wf[8];        // -w A-frags [mt*4+kt]
  s16x8 qf[8];        // q A-frags [mt*4+kt] (packed, coalesced)
  s16x8 a0, a1;       // Aloc A-frags
  s16x8 kf[8];        // kn^T A-frags [mtd]
};

DEVI void scan_load(SBuf& b, const u16* up, const u16* wp, const u16* qp,
                    const u16* ap, const u16* kp){
  b.uraw = *(const s16x8*)(up);
  #pragma unroll
  for (int j=0;j<8;++j) b.wf[j] = *(const s16x8*)(wp + j*512);
  #pragma unroll
  for (int j=0;j<8;++j) b.qf[j] = *(const s16x8*)(qp + j*512);
  b.a0 = *(const s16x8*)(ap);
  b.a1 = *(const s16x8*)(ap + 512);
  #pragma unroll
  for (int j=0;j<8;++j) b.kf[j] = *(const s16x8*)(kp + j*512);
}

// D-frag rows (m*16 + g*4 + ii) -> B-frag rows (g*8 + i) cross-lane relayout.
DEVI void scan_step(const SBuf& b, f32x4* Sf, u16* dptr,
                    int srcA, int srcB, bool hi, int r, int g){
  u32 pk0[8], pk1[8];
  #pragma unroll
  for (int m=0;m<8;++m){
    pk0[m] = pkbf(Sf[m][0], Sf[m][1]);
    pk1[m] = pkbf(Sf[m][2], Sf[m][3]);
  }
  s16x8 sf[4];
  #pragma unroll
  for (int kt=0;kt<4;++kt){
    u32 eA0 = __shfl(pk0[kt*2],   srcA, 64), oA0 = __shfl(pk0[kt*2+1], srcA, 64);
    u32 eA1 = __shfl(pk1[kt*2],   srcA, 64), oA1 = __shfl(pk1[kt*2+1], srcA, 64);
    u32 eB0 = __shfl(pk0[kt*2],   srcB, 64), oB0 = __shfl(pk0[kt*2+1], srcB, 64);
    u32 eB1 = __shfl(pk1[kt*2],   srcB, 64), oB1 = __shfl(pk1[kt*2+1], srcB, 64);
    union { u32 w[4]; s16x8 v; } uw;
    uw.w[0] = hi ? oA0 : eA0;
    uw.w[1] = hi ? oA1 : eA1;
    uw.w[2] = hi ? oB0 : eB0;
    uw.w[3] = hi ? oB1 : eB1;
    sf[kt] = uw.v;
  }
  f32x4 unA, unB, unA2 = {0,0,0,0}, unB2 = {0,0,0,0};
  #pragma unroll
  for (int i=0;i<4;++i){ unA[i] = bf2f((u16)b.uraw[i]); unB[i] = bf2f((u16)b.uraw[4+i]); }
  unA  = mfma16(b.wf[0], sf[0], unA);
  unA2 = mfma16(b.wf[2], sf[2], unA2);
  unB  = mfma16(b.wf[4], sf[0], unB);
  unB2 = mfma16(b.wf[6], sf[2], unB2);
  unA  = mfma16(b.wf[1], sf[1], unA);
  unA2 = mfma16(b.wf[3], sf[3], unA2);
  unB  = mfma16(b.wf[5], sf[1], unB);
  unB2 = mfma16(b.wf[7], sf[3], unB2);
  f32x4 o0 = {0,0,0,0}, o1 = {0,0,0,0};
  #pragma unroll
  for (int kt=0;kt<4;++kt){
    o0 = mfma16(b.qf[kt],   sf[kt], o0);
    o1 = mfma16(b.qf[4+kt], sf[kt], o1);
  }
  unA = unA + unA2;
  unB = unB + unB2;
  u32 a0p0 = pkbf(unA[0], unA[1]), a0p1 = pkbf(unA[2], unA[3]);
  u32 a1p0 = pkbf(unB[0], unB[1]), a1p1 = pkbf(unB[2], unB[3]);
  u32 w00 = __shfl(a0p0, srcA, 64), w10 = __shfl(a1p0, srcA, 64);
  u32 w01 = __shfl(a0p1, srcA, 64), w11 = __shfl(a1p1, srcA, 64);
  u32 w02 = __shfl(a0p0, srcB, 64), w12 = __shfl(a1p0, srcB, 64);
  u32 w03 = __shfl(a0p1, srcB, 64), w13 = __shfl(a1p1, srcB, 64);
  union { u32 w[4]; s16x8 v; } uu;
  uu.w[0] = hi ? w10 : w00;
  uu.w[1] = hi ? w11 : w01;
  uu.w[2] = hi ? w12 : w02;
  uu.w[3] = hi ? w13 : w03;
  const s16x8 uf = uu.v;
  o0 = mfma16(b.a0, uf, o0);
  o1 = mfma16(b.a1, uf, o1);
  #pragma unroll
  for (int i=0;i<4;++i){
    dptr[(size_t)(g*4+i)*128]    = f2bf(o0[i]);
    dptr[(size_t)(16+g*4+i)*128] = f2bf(o1[i]);
  }
  #pragma unroll
  for (int m=0;m<8;++m) Sf[m] = mfma16(b.kf[m], uf, Sf[m]);
}

__global__ __launch_bounds__(64, 1) void scan_k(
    const u16* __restrict__ qpk, const u16* __restrict__ wpk,
    const u16* __restrict__ updk, const u16* __restrict__ alocp,
    const u16* __restrict__ knpk, u16* __restrict__ delta)
{
  const int blk = blockIdx.x;
  const int sl = blk >> 5, bh = blk & 31;   // same-bh slices -> same XCD
  const int lane = threadIdx.x;
  const int g = lane >> 4, r = lane & 15;
  const int srcA = (g & 1)*32 + r;          // lane of source group g'=(g&1)*2
  const int srcB = srcA + 16;               // g'+1
  const bool hi = (g >= 2);
  f32x4 Sf[8];
  #pragma unroll
  for (int m=0;m<8;++m){ f32x4 z = {0,0,0,0}; Sf[m] = z; }

  const u16* upB = updk + ((size_t)bh*64*8 + sl)*512 + (size_t)lane*8;
  const u16* wpB = wpk  + (size_t)bh*64*4096 + (size_t)lane*8;
  const u16* qpB = qpk  + (size_t)bh*64*4096 + (size_t)lane*8;
  const u16* apB = alocp + (size_t)bh*64*1024 + (size_t)lane*8;
  const u16* kpB = knpk + (size_t)bh*64*4096 + (size_t)lane*8;
  u16*       dB  = delta + (size_t)bh*2048*128 + sl*16 + r;

  #define LD(buf, n) scan_load(buf, upB + (size_t)(n)*4096, wpB + (size_t)(n)*4096, \
                               qpB + (size_t)(n)*4096, apB + (size_t)(n)*1024, \
                               kpB + (size_t)(n)*4096)
  #define ST(buf, n) scan_step(buf, Sf, dB + (size_t)(n)*4096, srcA, srcB, hi, r, g)

  SBuf A, B, C;
  LD(A, 0); LD(B, 1);
  for (int ic = 0; ic < 63; ic += 3){
    LD(C, ic+2);
    ST(A, ic);
    if (ic + 3 < 64) LD(A, ic+3);
    ST(B, ic+1);
    if (ic + 4 < 64) LD(B, ic+4);
    ST(C, ic+2);
  }
  ST(A, 63);
  #undef LD
  #undef ST
}

// ---------------- FIR(3,31) + gating + double RMS -> o_final bf16 ----------------
__global__ __launch_bounds__(256) void fuse_k(
    const u16* __restrict__ vdir, const u16* __restrict__ delta,
    const float* __restrict__ fusv, const float* __restrict__ flo,
    const float* __restrict__ fsw, const float* __restrict__ flw,
    const float* __restrict__ wpf, const float* __restrict__ wno,
    u16* __restrict__ ofin)
{
  __shared__ float fl_t[31][128];   // transposed long-FIR weights for head h
  const int blk = blockIdx.x;
  const int lt = blk & 31, h = (blk >> 5) & 7, b = blk >> 8;
  const int t = threadIdx.x;
  const int w = t >> 6, lane = t & 63;
  const int d0 = lane * 2;
  const int l0 = lt*64 + w*16;          // this warp's first output row
  for (int j = t; j < 3968; j += 256){
    const int d = j / 31, i = j - d*31;
    fl_t[i][d] = flw[(size_t)h*3968 + j];
  }
  __syncthreads();
  float wlo[46], whi[46];
  #pragma unroll
  for (int j = 0; j < 46; ++j){
    const int ls = l0 - 30 + j;
    u32 x = 0;
    if (ls >= 0) x = *(const u32*)(vdir + ((size_t)b*2048 + ls)*1024 + h*128 + d0);
    wlo[j] = bf2f((u16)(x & 0xffffu));
    whi[j] = bf2f((u16)(x >> 16));
  }
  float lg0[16], lg1[16];
  #pragma unroll
  for (int rr = 0; rr < 16; ++rr){ lg0[rr] = 0.f; lg1[rr] = 0.f; }
  #pragma unroll
  for (int i = 0; i < 31; ++i){
    const float2 wv = *(const float2*)&fl_t[i][d0];
    #pragma unroll
    for (int rr = 0; rr < 16; ++rr){
      lg0[rr] += wlo[rr + i] * wv.x;
      lg1[rr] += whi[rr + i] * wv.y;
    }
  }
  const float wp0 = wpf[d0], wp1 = wpf[d0+1];
  const float wn0 = wno[d0], wn1 = wno[d0+1];
  float fs0[3], fs1[3];
  #pragma unroll
  for (int i=0;i<3;++i){
    fs0[i] = fsw[((size_t)h*128 + d0)*3 + i];
    fs1[i] = fsw[((size_t)h*128 + d0 + 1)*3 + i];
  }
  #pragma unroll
  for (int rr = 0; rr < 16; ++rr){
    const int l = l0 + rr;
    const float* fr = fusv + ((size_t)b*2048 + l)*32 + h*4;   // warp-uniform
    const float f0=fr[0], f1=fr[1], f2=fr[2], f3=fr[3];
    const float flv = flo[((size_t)b*2048 + l)*8 + h];
    const float p = sigm(f3) * (1.f - flv);
    const float mx = fmaxf(f0, fmaxf(f1, f2));
    const float e0 = __expf(f0-mx), e1 = __expf(f1-mx), e2 = __expf(f2-mx);
    const float inv = (1.f - p) / (e0 + e1 + e2);
    const float c0 = e0*inv, c1 = e1*inv, c2 = e2*inv;
    const float sh0 = wlo[rr+28]*fs0[0] + wlo[rr+29]*fs0[1] + wlo[rr+30]*fs0[2];
    const float sh1 = whi[rr+28]*fs1[0] + whi[rr+29]*fs1[1] + whi[rr+30]*fs1[2];
    const u32 dl2 = *(const u32*)(delta + (((size_t)(b*8 + h))*2048 + l)*128 + d0);
    const float dlx = bf2f((u16)(dl2 & 0xffffu)), dly = bf2f((u16)(dl2 >> 16));
    float o0 = c0*sh0 + c1*lg0[rr] + c2*dlx + p*wlo[rr+30];
    float o1 = c0*sh1 + c1*lg1[rr] + c2*dly + p*whi[rr+30];
    const float b0 = o0*wp0, b1 = o1*wp1;
    float ss = o0*o0 + o1*o1;
    float tt = b0*b0 + b1*b1;
    #pragma unroll
    for (int m=1; m<64; m<<=1){
      ss += __shfl_xor(ss, m, 64);
      tt += __shfl_xor(tt, m, 64);
    }
    const float r1 = rsqrtf(ss * (1.f/128.f) + 1e-5f);
    const float r2 = rsqrtf(r1*r1*tt * (1.f/128.f) + 1e-5f);
    const u32 h0 = f2bf(o0*r1*wp0*r2*wn0), h1 = f2bf(o1*r1*wp1*r2*wn1);
    *(u32*)(ofin + ((size_t)b*2048 + l)*1024 + h*128 + d0) = h0 | (h1 << 16);
  }
}

// ---------------- workspace layout (lifetime-aliased) ----------------
constexpr size_t OFF_HSB  = 0;          // hsb until fus1 GEMM; then qpk (16.7MB)
constexpr size_t OFF_WQT  = 16777216;   // wq/wk/wv transposed, contiguous (N=3072 B)
constexpr size_t OFF_WKT  = 18874368;
constexpr size_t OFF_WVT  = 20971520;
constexpr size_t OFF_W1T  = 23068672;
constexpr size_t OFF_WOT  = 27262976;
constexpr size_t OFF_QRAW = 29360128;   // q/k/v raw; after conv: fus1g; after fus2: delta
constexpr size_t OFF_KRAW = 46137344;
constexpr size_t OFF_VRAW = 62914560;   // after conv: wpk
constexpr size_t OFF_FUSV = 79691776;
constexpr size_t OFF_BETA = 80740352;
constexpr size_t OFF_FLO  = 81002496;
constexpr size_t OFF_VDIR = 81264640;   // bf16
constexpr size_t OFF_W2P  = 98041856;   // W2 B-frags, 128KB
constexpr size_t OFF_WBP  = 98172928;   // [Wb|Wfl] B-frags, 32KB
constexpr size_t OFF_QN   = 114819072;
constexpr size_t OFF_KN   = 131596288;
constexpr size_t OFF_ALOC = 148373504;
constexpr size_t OFF_UPDK = 152567808;  // bf16; after scan: ofin
constexpr size_t OFF_KNPK = 186122240;  // end: 202899456

extern "C" void kernel_launch(void* const* d_in, const int* in_sizes, int n_in,
                              void* d_out, int out_size, void* d_ws, size_t ws_size,
                              hipStream_t stream)
{
  const float* hs   = (const float*)d_in[0];
  const float* Wq   = (const float*)d_in[1];
  const float* Wk   = (const float*)d_in[2];
  const float* Wv   = (const float*)d_in[3];
  const float* Wb   = (const float*)d_in[4];
  const float* cq   = (const float*)d_in[5];
  const float* ck   = (const float*)d_in[6];
  const float* cv   = (const float*)d_in[7];
  const float* firs = (const float*)d_in[8];
  const float* firl = (const float*)d_in[9];
  const float* flW  = (const float*)d_in[10];
  const float* flb  = (const float*)d_in[11];
  const float* W1   = (const float*)d_in[12];
  const float* b1   = (const float*)d_in[13];
  const float* W2   = (const float*)d_in[14];
  const float* b2   = (const float*)d_in[15];
  const float* npf  = (const float*)d_in[16];
  const float* now  = (const float*)d_in[17];
  const float* Wo   = (const float*)d_in[18];

  char* ws = (char*)d_ws;
  u16*   hsb   = (u16*)(ws + OFF_HSB);
  u16*   wqT   = (u16*)(ws + OFF_WQT);
  u16*   wkT   = (u16*)(ws + OFF_WKT);
  u16*   wvT   = (u16*)(ws + OFF_WVT);
  u16*   w1T   = (u16*)(ws + OFF_W1T);
  u16*   woT   = (u16*)(ws + OFF_WOT);
  u16*   qraw  = (u16*)(ws + OFF_QRAW);
  u16*   kraw  = (u16*)(ws + OFF_KRAW);
  u16*   vraw  = (u16*)(ws + OFF_VRAW);
  u16*   fus1g = (u16*)(ws + OFF_QRAW);   // alias (qraw/kraw dead after conv)
  float* fusv  = (float*)(ws + OFF_FUSV);
  float* beta  = (float*)(ws + OFF_BETA);
  float* flo   = (float*)(ws + OFF_FLO);
  u16*   vdir  = (u16*)(ws + OFF_VDIR);   // bf16
  u16*   w2p   = (u16*)(ws + OFF_W2P);
  u16*   wbp   = (u16*)(ws + OFF_WBP);
  u16*   qn    = (u16*)(ws + OFF_QN);
  u16*   kn    = (u16*)(ws + OFF_KN);
  u16*   alocp = (u16*)(ws + OFF_ALOC);
  u16*   updk  = (u16*)(ws + OFF_UPDK);   // bf16
  u16*   wpk   = (u16*)(ws + OFF_VRAW);   // alias (vraw dead after conv); holds -w
  u16*   knpk  = (u16*)(ws + OFF_KNPK);
  u16*   qpk   = (u16*)(ws + OFF_HSB);    // alias (hsb dead after fus1 GEMM)
  u16*   delta = (u16*)(ws + OFF_QRAW);   // alias (fus1g dead after fus2), bf16
  u16*   ofin  = (u16*)(ws + OFF_UPDK);   // alias (updk dead after scan)

  // 1. merged prep: weight transposes + prepacks + hs->bf16 (one launch)
  prep_k<<<14496, 256, 0, stream>>>(Wq, Wk, Wv, W1, Wo, W2, Wb, flW, hs,
                                    wqT, wkT, wvT, w1T, woT, w2p, wbp, hsb);
  // 2. beta / floor (MFMA streamer)
  beta_floor_k<<<512, 64, 0, stream>>>(hsb, wbp, flb, beta, flo);
  // 3. merged QKV projection (N=3072, split epilogue)
  gemm_bt<3><<<dim3(24,64), 256, 0, stream>>>(hsb, wqT, qraw, nullptr, 8192, 3072, 1024);
  // 4. conv + silu + l2norm (16 rows/block, register history)
  conv_silu_k<<<512, 256, 0, stream>>>(qraw, kraw, vraw, cq, ck, cv, vdir, qn, kn);
  // 5. fusion MLP layer 1 (+bias, gelu) — last reader of hsb
  gemm_bt<1><<<dim3(16,64), 256, 0, stream>>>(hsb, w1T, fus1g, b1, 8192, 2048, 1024);
  // 6. fusion MLP layer 2 (MFMA streamer)
  fus2_k<<<512, 64, 0, stream>>>(fus1g, w2p, b2, fusv);
  // 7. UT transform + fragment packing (w negated; q packed to qpk over dead hsb)
  ut_k<<<2048, 256, 0, stream>>>(qn, kn, vdir, beta, alocp, updk, wpk, knpk, qpk);
  // 8. chunk-serial scan (256 x 1-wave, 3-deep prefetch)
  scan_k<<<256, 64, 0, stream>>>(qpk, wpk, updk, alocp, knpk, delta);
  // 9. FIR + gating + double RMS (register-window FIR)
  fuse_k<<<1024, 256, 0, stream>>>(vdir, delta, fusv, flo, firs, firl, npf, now, ofin);
  // 10. output projection
  gemm_bt<2><<<dim3(8,64), 256, 0, stream>>>(ofin, woT, d_out, nullptr, 8192, 1024, 1024);
}